// Round 12
// baseline (50.683 us; speedup 1.0000x reference)
//
#include <hip/hip_runtime.h>

#define T_STEPS 256
#define B_SIZE  128
#define N_TAGS  64
#define BN_     8192      // B*N
#define SEGS    16
#define SEGL    16
#define START_IDX 1
#define END_IDX 2

typedef float  f32x4  __attribute__((ext_vector_type(4)));
typedef float  f32x2  __attribute__((ext_vector_type(2)));
typedef short  bf16x8 __attribute__((ext_vector_type(8)));

union U8 { unsigned u[4]; bf16x8 v; };
union F4 { f32x4 v; f32x2 h[2]; float f[4]; };

__device__ __forceinline__ float fexp2(float x){float r;asm("v_exp_f32 %0, %1":"=v"(r):"v"(x));return r;}
__device__ __forceinline__ float flog2(float x){float r;asm("v_log_f32 %0, %1":"=v"(r):"v"(x));return r;}
__device__ __forceinline__ float frcp(float x){float r;asm("v_rcp_f32 %0, %1":"=v"(r):"v"(x));return r;}
__device__ __forceinline__ unsigned cvtpk(float lo,float hi){unsigned r;asm("v_cvt_pk_bf16_f32 %0, %1, %2":"=v"(r):"v"(lo),"v"(hi));return r;}
__device__ __forceinline__ void swap32(unsigned &a, unsigned &b){asm("v_permlane32_swap_b32 %0, %1":"+v"(a),"+v"(b));}
__device__ __forceinline__ void swap16(unsigned &a, unsigned &b){asm("v_permlane16_swap_b32 %0, %1":"+v"(a),"+v"(b));}
__device__ __forceinline__ f32x2 pkmul(f32x2 a, f32x2 b){f32x2 r;asm("v_pk_mul_f32 %0, %1, %2":"=v"(r):"v"(a),"v"(b));return r;}

#define MFMA16(A, B, C) __builtin_amdgcn_mfma_f32_16x16x32_bf16(A, B, C, 0, 0, 0)

__device__ __forceinline__ void wait24(){ asm volatile("s_waitcnt vmcnt(24)" ::: "memory"); __builtin_amdgcn_sched_barrier(0); }
__device__ __forceinline__ void wait16(){ asm volatile("s_waitcnt vmcnt(16)" ::: "memory"); __builtin_amdgcn_sched_barrier(0); }
__device__ __forceinline__ void wait8 (){ asm volatile("s_waitcnt vmcnt(8)"  ::: "memory"); __builtin_amdgcn_sched_barrier(0); }
__device__ __forceinline__ void wait0 (){ asm volatile("s_waitcnt vmcnt(0)"  ::: "memory"); __builtin_amdgcn_sched_barrier(0); }
__device__ __forceinline__ void wait28(){ asm volatile("s_waitcnt vmcnt(28)" ::: "memory"); __builtin_amdgcn_sched_barrier(0); }

// ---------------- shared macro blocks (operate on local vars) ----------------
#define IDP() do { _Pragma("unroll") \
  for (int c=0;c<2;++c) { _Pragma("unroll") \
    for (int cc=0;cc<4;++cc) { _Pragma("unroll") \
      for (int m=0;m<4;++m) { \
        int k0 = 32*c + 8*g + 2*m, n = 16*cc + col; \
        unsigned lo = (k0==n)?0x3F80u:0u, hi=(k0+1==n)?0x3F80u:0u; \
        P[c][cc].u[m] = lo | (hi<<16); } } } } while(0)

#define EVG() do { _Pragma("unroll") \
  for (int tt=0;tt<4;++tt) { _Pragma("unroll") \
    for (int r=0;r<4;++r) ev[tt][r] = __shfl(eul, 16*tt + 4*g + r, 64); } } while(0)

#define EVSCALE() do { _Pragma("unroll") \
  for (int tt=0;tt<4;++tt) { f32x2 e01,e23; \
    e01[0]=ev[tt][0]; e01[1]=ev[tt][1]; e23[0]=ev[tt][2]; e23[1]=ev[tt][3]; \
    _Pragma("unroll") for (int cc=0;cc<4;++cc) { \
      Dt[tt][cc].h[0]=pkmul(Dt[tt][cc].h[0],e01); \
      Dt[tt][cc].h[1]=pkmul(Dt[tt][cc].h[1],e23); } } } while(0)

#define RESC() do { float mm = Dt[0][0].f[0]; \
  _Pragma("unroll") for (int tt=0;tt<4;++tt) { _Pragma("unroll") for (int cc=0;cc<4;++cc) { \
    _Pragma("unroll") for (int r=0;r<4;++r) mm = fmaxf(mm, Dt[tt][cc].f[r]); } } \
  _Pragma("unroll") for (int m2=1;m2<64;m2<<=1) mm = fmaxf(mm, __shfl_xor(mm,m2,64)); \
  float inv = frcp(mm); C += LN2*flog2(mm); \
  f32x2 iv; iv[0]=inv; iv[1]=inv; \
  _Pragma("unroll") for (int tt=0;tt<4;++tt) { _Pragma("unroll") for (int cc=0;cc<4;++cc) { \
    Dt[tt][cc].h[0]=pkmul(Dt[tt][cc].h[0],iv); Dt[tt][cc].h[1]=pkmul(Dt[tt][cc].h[1],iv); } } } while(0)

#define CVTP() do { _Pragma("unroll") \
  for (int cc=0;cc<4;++cc) { \
    unsigned p00 = cvtpk(Dt[0][cc].f[0], Dt[0][cc].f[1]); \
    unsigned p01 = cvtpk(Dt[0][cc].f[2], Dt[0][cc].f[3]); \
    unsigned p10 = cvtpk(Dt[1][cc].f[0], Dt[1][cc].f[1]); \
    unsigned p11 = cvtpk(Dt[1][cc].f[2], Dt[1][cc].f[3]); \
    unsigned p20 = cvtpk(Dt[2][cc].f[0], Dt[2][cc].f[1]); \
    unsigned p21 = cvtpk(Dt[2][cc].f[2], Dt[2][cc].f[3]); \
    unsigned p30 = cvtpk(Dt[3][cc].f[0], Dt[3][cc].f[1]); \
    unsigned p31 = cvtpk(Dt[3][cc].f[2], Dt[3][cc].f[3]); \
    swap32(p00, p10); swap32(p01, p11); swap32(p20, p30); swap32(p21, p31); \
    swap16(p00, p10); swap16(p01, p11); swap16(p20, p30); swap16(p21, p31); \
    P[0][cc].u[0]=p00; P[0][cc].u[1]=p01; P[0][cc].u[2]=p10; P[0][cc].u[3]=p11; \
    P[1][cc].u[0]=p20; P[1][cc].u[1]=p21; P[1][cc].u[2]=p30; P[1][cc].u[3]=p31; } } while(0)

#define MFMAB() do { _Pragma("unroll") \
  for (int cc=0;cc<4;++cc) { _Pragma("unroll") \
    for (int tt=0;tt<4;++tt) { \
      f32x4 acc = MFMA16(EA[tt][0].v, P[0][cc].v, zf); \
      Dt[tt][cc].v = MFMA16(EA[tt][1].v, P[1][cc].v, acc); } } } while(0)

#define STOREP(DST) do { _Pragma("unroll") \
  for (int cc=0;cc<4;++cc) { _Pragma("unroll") \
    for (int c=0;c<2;++c) { \
      uint4 q; q.x=P[c][cc].u[0]; q.y=P[c][cc].u[1]; q.z=P[c][cc].u[2]; q.w=P[c][cc].u[3]; \
      *(uint4*)((DST) + (cc*2+c)*256) = q; } } } while(0)

// Global M-buffer load (R9-verified layout): frag fp at u32 offset fp*256 + lane*4
#define MLOAD(SL, SEG) do { \
    const unsigned* _mp = mbase + (size_t)(SEG) * 2048; \
    const unsigned* _mq = _mp + 1024; \
    asm volatile("global_load_dwordx4 %0, %1, off"             : "=v"(SL[0].v) : "v"(_mp)); \
    asm volatile("global_load_dwordx4 %0, %1, off offset:1024" : "=v"(SL[1].v) : "v"(_mp)); \
    asm volatile("global_load_dwordx4 %0, %1, off offset:2048" : "=v"(SL[2].v) : "v"(_mp)); \
    asm volatile("global_load_dwordx4 %0, %1, off offset:3072" : "=v"(SL[3].v) : "v"(_mp)); \
    asm volatile("global_load_dwordx4 %0, %1, off"             : "=v"(SL[4].v) : "v"(_mq)); \
    asm volatile("global_load_dwordx4 %0, %1, off offset:1024" : "=v"(SL[5].v) : "v"(_mq)); \
    asm volatile("global_load_dwordx4 %0, %1, off offset:2048" : "=v"(SL[6].v) : "v"(_mq)); \
    asm volatile("global_load_dwordx4 %0, %1, off offset:3072" : "=v"(SL[7].v) : "v"(_mq)); \
} while (0)

#define PSTEP(WN, SL, LD) do { \
    wait##WN(); \
    U8 Af0, Af1; \
    { float vs = (g < 2) ? a0 : a1; \
      float f0=__shfl(vs,sbase+0,64), f1=__shfl(vs,sbase+1,64); \
      float f2=__shfl(vs,sbase+2,64), f3=__shfl(vs,sbase+3,64); \
      float f4=__shfl(vs,sbase+4,64), f5=__shfl(vs,sbase+5,64); \
      float f6=__shfl(vs,sbase+6,64), f7=__shfl(vs,sbase+7,64); \
      Af0.u[0]=cvtpk(f0,f1); Af0.u[1]=cvtpk(f2,f3); Af0.u[2]=cvtpk(f4,f5); Af0.u[3]=cvtpk(f6,f7); } \
    { float vs = (g < 2) ? a2 : a3; \
      float f0=__shfl(vs,sbase+0,64), f1=__shfl(vs,sbase+1,64); \
      float f2=__shfl(vs,sbase+2,64), f3=__shfl(vs,sbase+3,64); \
      float f4=__shfl(vs,sbase+4,64), f5=__shfl(vs,sbase+5,64); \
      float f6=__shfl(vs,sbase+6,64), f7=__shfl(vs,sbase+7,64); \
      Af1.u[0]=cvtpk(f0,f1); Af1.u[1]=cvtpk(f2,f3); Af1.u[2]=cvtpk(f4,f5); Af1.u[3]=cvtpk(f6,f7); } \
    f32x4 q0 = MFMA16(Af0.v, SL[0].v, zf); q0 = MFMA16(Af1.v, SL[1].v, q0); \
    f32x4 q1 = MFMA16(Af0.v, SL[2].v, zf); q1 = MFMA16(Af1.v, SL[3].v, q1); \
    f32x4 q2 = MFMA16(Af0.v, SL[4].v, zf); q2 = MFMA16(Af1.v, SL[5].v, q2); \
    f32x4 q3 = MFMA16(Af0.v, SL[6].v, zf); q3 = MFMA16(Af1.v, SL[7].v, q3); \
    float n0 = q0[0], n1 = q1[0], n2 = q2[0], n3 = q3[0]; \
    float mm = fmaxf(fmaxf(n0, n1), fmaxf(n2, n3)); \
    mm = fmaxf(mm, __shfl_xor(mm, 1, 64)); mm = fmaxf(mm, __shfl_xor(mm, 2, 64)); \
    mm = fmaxf(mm, __shfl_xor(mm, 4, 64)); mm = fmaxf(mm, __shfl_xor(mm, 8, 64)); \
    float inv = frcp(mm); C2 += LN2 * flog2(mm); \
    a0 = n0 * inv; a1 = n1 * inv; a2 = n2 * inv; a3 = n3 * inv; \
    if ((LD) >= 0) { MLOAD(SL, LD); } \
} while (0)

// =========================================================================
// Fused, one block per batch (512 thr, 8 waves). M staged through GLOBAL
// d_ws with the R9-verified layout — NOT LDS (the one unproven pattern in
// the two failed fused attempts). __syncthreads gives block-level global
// visibility and resets vmcnt (compiler drains before s_barrier), so the
// fold's counted waits stay exact.
// =========================================================================
__global__ __launch_bounds__(512, 1)
void crf_fused(const float* __restrict__ u, const float* __restrict__ trans,
               const int* __restrict__ lengths, unsigned* __restrict__ Mbuf,
               float* __restrict__ out) {
    const int tid  = threadIdx.x;
    const int wid  = tid >> 6;
    const int lane = tid & 63;
    const int col  = lane & 15;
    const int g    = lane >> 4;
    const int b    = blockIdx.x;
    const float K = 1.4426950408889634f, LN2 = 0.6931471805599453f;
    const f32x4 zf = {0.f, 0.f, 0.f, 0.f};

    __shared__ __align__(16) float sT[N_TAGS * N_TAGS];   // 16 KiB
    __shared__ float sX[64], sY[64], sC[2], sCseg[SEGS];

    {   // stage trans
        const float4* t4 = (const float4*)trans;
        float4* s4 = (float4*)sT;
        s4[tid] = t4[tid];
        s4[tid + 512] = t4[tid + 512];
    }
    __syncthreads();

    const int  len   = lengths[b];
    const bool front = (wid < 4);

    // E (back waves) or E^T (front waves) A-frags — verbatim R9.
    U8 EA[4][2];
    if (!front) {
#pragma unroll
        for (int tt = 0; tt < 4; ++tt) {
#pragma unroll
            for (int c = 0; c < 2; ++c) {
                const float* p = &sT[(16*tt + col)*64 + 32*c + 8*g];
#pragma unroll
                for (int j2 = 0; j2 < 4; ++j2)
                    EA[tt][c].u[j2] = cvtpk(fexp2(p[2*j2]*K), fexp2(p[2*j2+1]*K));
            }
        }
    } else {
#pragma unroll
        for (int tt = 0; tt < 4; ++tt) {
#pragma unroll
            for (int c = 0; c < 2; ++c) {
#pragma unroll
                for (int j2 = 0; j2 < 4; ++j2) {
                    const int a0i = 32*c + 8*g + 2*j2;
                    EA[tt][c].u[j2] = cvtpk(fexp2(sT[a0i*64 + 16*tt + col] * K),
                                            fexp2(sT[(a0i+1)*64 + 16*tt + col] * K));
                }
            }
        }
    }

    const float* ub = u + (size_t)b * 64 + lane;

    // ---------------- phase 1: two segments per wave, M -> GLOBAL ----------------
#pragma unroll
    for (int q = 0; q < 2; ++q) {
        const int s = (front ? 0 : 8) + 2*(wid & 3) + q;
        int n_act = len - 1 - s*SEGL;
        n_act = max(0, min(SEGL, n_act));
        unsigned* dst = Mbuf + ((size_t)b*SEGS + s) * 2048 + lane * 4;

        U8 P[2][4];
        float C = 0.0f;

        if (n_act == 0) {
            IDP();
        } else if (!front) {
            IDP();
            F4 Dt[4][4];
            float ev[4][4];
            const int t0 = 16*s + 1;
            float uc = ub[(size_t)t0 * BN_];
            float un = ub[(size_t)min(t0 + 1, T_STEPS - 1) * BN_];
            for (int i = 0; i < n_act; ++i) {
                float eul = fexp2(uc * K);
                uc = un; un = ub[(size_t)min(t0 + i + 2, T_STEPS - 1) * BN_];
                EVG();
                MFMAB();                 // Dt = E * P
                EVSCALE();               // Dt = diag(eu) * Dt
                if ((i & 7) == 7) RESC();
                CVTP();                  // P = bf16(Dt)
            }
        } else {
            F4 Dt[4][4];
            float ev[4][4];
#pragma unroll
            for (int tt = 0; tt < 4; ++tt) {
#pragma unroll
                for (int cc = 0; cc < 4; ++cc) {
#pragma unroll
                    for (int r = 0; r < 4; ++r)
                        Dt[tt][cc].f[r] = (tt == cc && 4*g + r == col) ? 1.0f : 0.0f;
                }
            }
            const int th = 16*s + n_act;
            float uc = ub[(size_t)th * BN_];
            float un = ub[(size_t)max(th - 1, 0) * BN_];
            for (int i = 0; i < n_act; ++i) {
                float eul = fexp2(uc * K);
                uc = un; un = ub[(size_t)max(th - i - 2, 0) * BN_];
                EVG();
                EVSCALE();               // Dt = diag(eu_t) * Dt
                if ((i & 7) == 7) RESC();
                CVTP();                  // P = bf16(Dt)
                MFMAB();                 // Dt = E^T * P
            }
            CVTP();                      // final convert
        }

        STOREP(dst);
        if (lane == 0) sCseg[s] = C;
    }
    __syncthreads();   // drains vmcnt; global M + sCseg visible block-wide

    // ---------------- phase 2: two 8-step folds (verbatim R9 comb) ----------------
    if (wid == 0 || wid == 4) {
        float a0, a1, a2, a3;
        if (wid == 0) {   // x = w0 = exp(u0 + tStart)
            a0 = fexp2((u[(size_t)b*64 +  0 + col] + trans[( 0 + col)*64 + START_IDX]) * K);
            a1 = fexp2((u[(size_t)b*64 + 16 + col] + trans[(16 + col)*64 + START_IDX]) * K);
            a2 = fexp2((u[(size_t)b*64 + 32 + col] + trans[(32 + col)*64 + START_IDX]) * K);
            a3 = fexp2((u[(size_t)b*64 + 48 + col] + trans[(48 + col)*64 + START_IDX]) * K);
        } else {          // a = f = exp(tEnd)
            a0 = fexp2(trans[END_IDX*64 +  0 + col] * K);
            a1 = fexp2(trans[END_IDX*64 + 16 + col] * K);
            a2 = fexp2(trans[END_IDX*64 + 32 + col] * K);
            a3 = fexp2(trans[END_IDX*64 + 48 + col] * K);
        }
        const int sbase = (lane & 48) | ((g & 1) << 3);
        const unsigned* mbase = Mbuf + (size_t)b * SEGS * 2048 + lane * 4;
        float C2 = 0.0f;

        U8 MP0[8], MP1[8], MP2[8], MP3[8];
        if (wid == 0) {
            MLOAD(MP0, 0); MLOAD(MP1, 1); MLOAD(MP2, 2); MLOAD(MP3, 3);
            PSTEP(24, MP0,  4); PSTEP(24, MP1,  5); PSTEP(24, MP2,  6); PSTEP(24, MP3,  7);
            PSTEP(24, MP0, -1); PSTEP(16, MP1, -1); PSTEP(8,  MP2, -1); PSTEP(0,  MP3, -1);
        } else {
            MLOAD(MP0, 15); MLOAD(MP1, 14); MLOAD(MP2, 13); MLOAD(MP3, 12);
            PSTEP(24, MP0, 11); PSTEP(24, MP1, 10); PSTEP(24, MP2,  9); PSTEP(24, MP3,  8);
            PSTEP(24, MP0, -1); PSTEP(16, MP1, -1); PSTEP(8,  MP2, -1); PSTEP(0,  MP3, -1);
        }

        if (g == 0) {
            float* dstv = (wid == 0) ? sX : sY;
            dstv[ 0 + col] = a0; dstv[16 + col] = a1;
            dstv[32 + col] = a2; dstv[48 + col] = a3;
        }
        if (wid == 4) {
            float cs = (lane < SEGS) ? sCseg[lane] : 0.0f;
#pragma unroll
            for (int m = 1; m < 32; m <<= 1) cs += __shfl_xor(cs, m, 64);
            if (lane == 0) sC[1] = C2 + cs;
        } else {
            if (lane == 0) sC[0] = C2;
        }
    }
    __syncthreads();

    if (tid < 16) {
        float part = 0.0f;
#pragma unroll
        for (int cc = 0; cc < 4; ++cc)
            part = fmaf(sX[16*cc + tid], sY[16*cc + tid], part);
        part += __shfl_xor(part, 1, 64);
        part += __shfl_xor(part, 2, 64);
        part += __shfl_xor(part, 4, 64);
        part += __shfl_xor(part, 8, 64);
        if (tid == 0) out[b] = sC[0] + sC[1] + LN2 * flog2(part);
    }
}

// =========================================================================
// Fallback (ws too small): R6-style serial fwd/bwd kernel, no workspace.
// =========================================================================
#define LOAD4O(RB, PTR) do { const float* _p = (PTR); \
    asm volatile("global_load_dwordx4 %0, %1, off"            : "=v"(RB[0].v) : "v"(_p)); \
    asm volatile("global_load_dwordx4 %0, %1, off offset:64"  : "=v"(RB[1].v) : "v"(_p)); \
    asm volatile("global_load_dwordx4 %0, %1, off offset:128" : "=v"(RB[2].v) : "v"(_p)); \
    asm volatile("global_load_dwordx4 %0, %1, off offset:192" : "=v"(RB[3].v) : "v"(_p)); \
} while (0)

template<bool RS, bool SNAPW>
__device__ __forceinline__ void stepfn(F4 (&D)[4], F4 (&UB)[4], const U8 (&A)[4][2],
                                       bool ccw, F4 (&wS)[4], float &snapC, float &C) {
    const float K = 1.4426950408889634f, LN2 = 0.6931471805599453f;
    const f32x4 zf = {0.f, 0.f, 0.f, 0.f};
    F4 W[4];
#pragma unroll
    for (int tt = 0; tt < 4; ++tt) {
#pragma unroll
        for (int r = 0; r < 4; ++r) W[tt].f[r] = D[tt].f[r] * fexp2(UB[tt].f[r] * K);
    }
    if (RS) {
        float m0 = fmaxf(fmaxf(W[0].f[0], W[0].f[1]), fmaxf(W[0].f[2], W[0].f[3]));
        float m1 = fmaxf(fmaxf(W[1].f[0], W[1].f[1]), fmaxf(W[1].f[2], W[1].f[3]));
        float m2 = fmaxf(fmaxf(W[2].f[0], W[2].f[1]), fmaxf(W[2].f[2], W[2].f[3]));
        float m3 = fmaxf(fmaxf(W[3].f[0], W[3].f[1]), fmaxf(W[3].f[2], W[3].f[3]));
        float mm = fmaxf(fmaxf(m0, m1), fmaxf(m2, m3));
        mm = fmaxf(mm, __shfl_xor(mm, 16, 64));
        mm = fmaxf(mm, __shfl_xor(mm, 32, 64));
        float inv = frcp(mm);
        C += LN2 * flog2(mm);
        f32x2 iv; iv[0] = inv; iv[1] = inv;
#pragma unroll
        for (int tt = 0; tt < 4; ++tt) {
            W[tt].h[0] = pkmul(W[tt].h[0], iv);
            W[tt].h[1] = pkmul(W[tt].h[1], iv);
        }
    }
    if (SNAPW) {
        if (__ballot(ccw)) {
#pragma unroll
            for (int tt = 0; tt < 4; ++tt) {
#pragma unroll
                for (int r = 0; r < 4; ++r)
                    wS[tt].f[r] = ccw ? W[tt].f[r] : wS[tt].f[r];
            }
            snapC = ccw ? C : snapC;
        }
    }
    unsigned p00 = cvtpk(W[0].f[0], W[0].f[1]), p01 = cvtpk(W[0].f[2], W[0].f[3]);
    unsigned p10 = cvtpk(W[1].f[0], W[1].f[1]), p11 = cvtpk(W[1].f[2], W[1].f[3]);
    unsigned p20 = cvtpk(W[2].f[0], W[2].f[1]), p21 = cvtpk(W[2].f[2], W[2].f[3]);
    unsigned p30 = cvtpk(W[3].f[0], W[3].f[1]), p31 = cvtpk(W[3].f[2], W[3].f[3]);
    swap32(p00, p10); swap32(p01, p11); swap32(p20, p30); swap32(p21, p31);
    swap16(p00, p10); swap16(p01, p11); swap16(p20, p30); swap16(p21, p31);
    U8 b0, b1;
    b0.u[0] = p00; b0.u[1] = p01; b0.u[2] = p10; b0.u[3] = p11;
    b1.u[0] = p20; b1.u[1] = p21; b1.u[2] = p30; b1.u[3] = p31;
#pragma unroll
    for (int tt = 0; tt < 4; ++tt) {
        f32x4 acc = MFMA16(A[tt][0].v, b0.v, zf);
        D[tt].v   = MFMA16(A[tt][1].v, b1.v, acc);
    }
}

__device__ __forceinline__ void make_frags(const float* sT, int wid, int col, int g,
                                           U8 (&A)[4][2], F4 (&D)[4]) {
    const float K = 1.4426950408889634f;
    if (wid == 0) {
#pragma unroll
        for (int tt = 0; tt < 4; ++tt) {
#pragma unroll
            for (int c = 0; c < 2; ++c) {
                const float* p = &sT[(16*tt + col)*64 + 32*c + 8*g];
#pragma unroll
                for (int j2 = 0; j2 < 4; ++j2)
                    A[tt][c].u[j2] = cvtpk(fexp2(p[2*j2]*K), fexp2(p[2*j2+1]*K));
            }
        }
#pragma unroll
        for (int tt = 0; tt < 4; ++tt) {
#pragma unroll
            for (int r = 0; r < 4; ++r)
                D[tt].f[r] = fexp2(sT[(16*tt + 4*g + r)*64 + START_IDX] * K);
        }
    } else {
#pragma unroll
        for (int tt = 0; tt < 4; ++tt) {
#pragma unroll
            for (int c = 0; c < 2; ++c) {
#pragma unroll
                for (int j2 = 0; j2 < 4; ++j2) {
                    const int a0 = 32*c + 8*g + 2*j2;
                    A[tt][c].u[j2] = cvtpk(fexp2(sT[a0*64 + 16*tt + col] * K),
                                           fexp2(sT[(a0+1)*64 + 16*tt + col] * K));
                }
            }
        }
#pragma unroll
        for (int tt = 0; tt < 4; ++tt) {
#pragma unroll
            for (int r = 0; r < 4; ++r)
                D[tt].f[r] = fexp2(sT[END_IDX*64 + 16*tt + 4*g + r] * K);
        }
    }
}

__launch_bounds__(128, 1)
__global__ void crf_fb_old(const float* __restrict__ src,
                           const float* __restrict__ trans,
                           const int* __restrict__ lengths,
                           float* __restrict__ out) {
    const int tid  = threadIdx.x;
    const int wid  = tid >> 6;
    const int lane = tid & 63;
    const int col  = lane & 15;
    const int g    = lane >> 4;
    const int bidx = blockIdx.x * 16 + col;

    __shared__ __align__(16) float sT[N_TAGS * N_TAGS];
    __shared__ __align__(16) float sW[N_TAGS * 16];
    __shared__ __align__(16) float sV[N_TAGS * 16];
    __shared__ float sCf[16], sCb[16];

    {
        const float4* t4 = (const float4*)trans;
        float4* s4 = (float4*)sT;
#pragma unroll
        for (int k2 = 0; k2 < 8; ++k2) s4[k2 * 128 + tid] = t4[k2 * 128 + tid];
    }
    __syncthreads();

    const float LN2 = 0.6931471805599453f;
    const int len = lengths[bidx];
    const int M   = (len - 1) >> 1;
    const int Kb  = (len - 1) - M;

    U8 A[4][2];
    F4 D[4];
    make_frags(sT, wid, col, g, A, D);

    int need = (wid == 0) ? (M + 1) : Kb;
    int mx = need;
#pragma unroll
    for (int m = 1; m < 64; m <<= 1) mx = max(mx, __shfl_xor(mx, m, 64));
    mx = __builtin_amdgcn_readfirstlane(mx);

    const int base = bidx * 64 + 4 * g;
    float C = 0.0f, snapC = 0.0f;
    F4 wS[4];
#pragma unroll
    for (int tt = 0; tt < 4; ++tt) wS[tt] = D[tt];

    F4 R0[4], R1[4], R2[4], R3[4], R4_[4], R5[4], R6[4], R7[4];

    if (wid == 0) {
        const float* pf = src + base;
        LOAD4O(R0, pf);            LOAD4O(R1, pf + BN_);
        LOAD4O(R2, pf + 2*BN_);    LOAD4O(R3, pf + 3*BN_);
        LOAD4O(R4_, pf + 4*BN_);   LOAD4O(R5, pf + 5*BN_);
        LOAD4O(R6, pf + 6*BN_);    LOAD4O(R7, pf + 7*BN_);
        const float* pn = pf + 8 * BN_;
        const int Nf = (mx + 7) & ~7;
        for (int s = 0; s < Nf; s += 8) {
#define FSTEP(QQ, RB, RSF) do { \
            const int t_ = s + (QQ); \
            wait28(); \
            stepfn<RSF, true>(D, RB, A, (t_ == M), wS, snapC, C); \
            LOAD4O(RB, pn); pn += BN_; \
        } while (0)
            FSTEP(0, R0, false); FSTEP(1, R1, false); FSTEP(2, R2, false);
            FSTEP(3, R3, false); FSTEP(4, R4_, false); FSTEP(5, R5, false);
            FSTEP(6, R6, false); FSTEP(7, R7, true);
#undef FSTEP
        }
        wait0();
    } else {
        const float* pb = src + base;
        {
#define PRIME(RB, q) do { int tq = max(len - 1 - (q), 0); LOAD4O(RB, pb + tq * BN_); } while (0)
            PRIME(R0, 0); PRIME(R1, 1); PRIME(R2, 2); PRIME(R3, 3);
            PRIME(R4_, 4); PRIME(R5, 5); PRIME(R6, 6); PRIME(R7, 7);
#undef PRIME
        }
        int tP = len - 9;
        const int Nb = (mx + 7) & ~7;
        for (int s = 0; s < Nb; s += 8) {
#define BSTEP(QQ, RB, RSF) do { \
            const int k_ = s + (QQ) + 1; \
            wait28(); \
            stepfn<RSF, false>(D, RB, A, false, wS, snapC, C); \
            if (__ballot(k_ == Kb)) { \
                const bool cc = (k_ == Kb); \
                _Pragma("unroll") \
                for (int tt = 0; tt < 4; ++tt) { \
                    _Pragma("unroll") \
                    for (int r = 0; r < 4; ++r) \
                        wS[tt].f[r] = cc ? D[tt].f[r] : wS[tt].f[r]; \
                } \
                snapC = cc ? C : snapC; \
            } \
            int tc = max(tP, 0); LOAD4O(RB, pb + tc * BN_); tP -= 1; \
        } while (0)
            BSTEP(0, R0, false); BSTEP(1, R1, false); BSTEP(2, R2, false);
            BSTEP(3, R3, false); BSTEP(4, R4_, false); BSTEP(5, R5, false);
            BSTEP(6, R6, false); BSTEP(7, R7, true);
#undef BSTEP
        }
        wait0();
    }

    {
        float* dstv = (wid == 0) ? sW : sV;
#pragma unroll
        for (int tt = 0; tt < 4; ++tt) {
#pragma unroll
            for (int r = 0; r < 4; ++r)
                dstv[(16*tt + 4*g + r) * 16 + col] = wS[tt].f[r];
        }
        if (g == 0) { if (wid == 0) sCf[col] = snapC; else sCb[col] = snapC; }
    }
    __syncthreads();
    if (wid == 0) {
        float part = 0.0f;
#pragma unroll
        for (int j = 0; j < 16; ++j) {
            const int n = g * 16 + j;
            part = fmaf(sW[n * 16 + col], sV[n * 16 + col], part);
        }
        part += __shfl_xor(part, 16, 64);
        part += __shfl_xor(part, 32, 64);
        if (g == 0) out[bidx] = sCf[col] + sCb[col] + LN2 * flog2(part);
    }
}

extern "C" void kernel_launch(void* const* d_in, const int* in_sizes, int n_in,
                              void* d_out, int out_size, void* d_ws, size_t ws_size,
                              hipStream_t stream) {
    const float* unary   = (const float*)d_in[0];
    const float* trans   = (const float*)d_in[1];
    const int*   lengths = (const int*)d_in[2];
    float* out = (float*)d_out;

    const size_t need = (size_t)B_SIZE * SEGS * 2048 * 4;   // 16.78 MB
    if (ws_size >= need) {
        unsigned* Mbuf = (unsigned*)d_ws;
        hipLaunchKernelGGL(crf_fused, dim3(B_SIZE), dim3(512), 0, stream,
                           unary, trans, lengths, Mbuf, out);
    } else {
        hipLaunchKernelGGL(crf_fb_old, dim3(B_SIZE / 16), dim3(128), 0, stream,
                           unary, trans, lengths, out);
    }
}

// Round 13
// 33.369 us; speedup vs baseline: 1.5189x; 1.5189x over previous
//
#include <hip/hip_runtime.h>

#define T_STEPS 256
#define B_SIZE  128
#define N_TAGS  64
#define BN_     8192      // B*N
#define SEGS    16
#define SEGL    16
#define START_IDX 1
#define END_IDX 2

typedef float  f32x4  __attribute__((ext_vector_type(4)));
typedef float  f32x2  __attribute__((ext_vector_type(2)));
typedef short  bf16x8 __attribute__((ext_vector_type(8)));

union U8 { unsigned u[4]; bf16x8 v; };
union F4 { f32x4 v; f32x2 h[2]; float f[4]; };

__device__ __forceinline__ float fexp2(float x){float r;asm("v_exp_f32 %0, %1":"=v"(r):"v"(x));return r;}
__device__ __forceinline__ float flog2(float x){float r;asm("v_log_f32 %0, %1":"=v"(r):"v"(x));return r;}
__device__ __forceinline__ float frcp(float x){float r;asm("v_rcp_f32 %0, %1":"=v"(r):"v"(x));return r;}
__device__ __forceinline__ unsigned cvtpk(float lo,float hi){unsigned r;asm("v_cvt_pk_bf16_f32 %0, %1, %2":"=v"(r):"v"(lo),"v"(hi));return r;}
__device__ __forceinline__ void swap32(unsigned &a, unsigned &b){asm("v_permlane32_swap_b32 %0, %1":"+v"(a),"+v"(b));}
__device__ __forceinline__ void swap16(unsigned &a, unsigned &b){asm("v_permlane16_swap_b32 %0, %1":"+v"(a),"+v"(b));}
__device__ __forceinline__ f32x2 pkmul(f32x2 a, f32x2 b){f32x2 r;asm("v_pk_mul_f32 %0, %1, %2":"=v"(r):"v"(a),"v"(b));return r;}

#define MFMA16(A, B, C) __builtin_amdgcn_mfma_f32_16x16x32_bf16(A, B, C, 0, 0, 0)

__device__ __forceinline__ void wait24(){ asm volatile("s_waitcnt vmcnt(24)" ::: "memory"); __builtin_amdgcn_sched_barrier(0); }
__device__ __forceinline__ void wait16(){ asm volatile("s_waitcnt vmcnt(16)" ::: "memory"); __builtin_amdgcn_sched_barrier(0); }
__device__ __forceinline__ void wait8 (){ asm volatile("s_waitcnt vmcnt(8)"  ::: "memory"); __builtin_amdgcn_sched_barrier(0); }
__device__ __forceinline__ void wait0 (){ asm volatile("s_waitcnt vmcnt(0)"  ::: "memory"); __builtin_amdgcn_sched_barrier(0); }
__device__ __forceinline__ void wait28(){ asm volatile("s_waitcnt vmcnt(28)" ::: "memory"); __builtin_amdgcn_sched_barrier(0); }

// ---------------- shared macro blocks (operate on local vars) ----------------
#define IDP() do { _Pragma("unroll") \
  for (int c=0;c<2;++c) { _Pragma("unroll") \
    for (int cc=0;cc<4;++cc) { _Pragma("unroll") \
      for (int m=0;m<4;++m) { \
        int k0 = 32*c + 8*g + 2*m, n = 16*cc + col; \
        unsigned lo = (k0==n)?0x3F80u:0u, hi=(k0+1==n)?0x3F80u:0u; \
        P[c][cc].u[m] = lo | (hi<<16); } } } } while(0)

#define EVG() do { _Pragma("unroll") \
  for (int tt=0;tt<4;++tt) { _Pragma("unroll") \
    for (int r=0;r<4;++r) ev[tt][r] = __shfl(eul, 16*tt + 4*g + r, 64); } } while(0)

#define EVSCALE() do { _Pragma("unroll") \
  for (int tt=0;tt<4;++tt) { f32x2 e01,e23; \
    e01[0]=ev[tt][0]; e01[1]=ev[tt][1]; e23[0]=ev[tt][2]; e23[1]=ev[tt][3]; \
    _Pragma("unroll") for (int cc=0;cc<4;++cc) { \
      Dt[tt][cc].h[0]=pkmul(Dt[tt][cc].h[0],e01); \
      Dt[tt][cc].h[1]=pkmul(Dt[tt][cc].h[1],e23); } } } while(0)

// Constant rescale: x *= 2^-64, C += 64*ln2.  No cross-lane reduce.
#define RESCC() do { C += 44.361419555836498f; \
  f32x2 iv; iv[0]=5.421010862427522e-20f; iv[1]=5.421010862427522e-20f; \
  _Pragma("unroll") for (int tt=0;tt<4;++tt) { _Pragma("unroll") for (int cc=0;cc<4;++cc) { \
    Dt[tt][cc].h[0]=pkmul(Dt[tt][cc].h[0],iv); Dt[tt][cc].h[1]=pkmul(Dt[tt][cc].h[1],iv); } } } while(0)

#define CVTP() do { _Pragma("unroll") \
  for (int cc=0;cc<4;++cc) { \
    unsigned p00 = cvtpk(Dt[0][cc].f[0], Dt[0][cc].f[1]); \
    unsigned p01 = cvtpk(Dt[0][cc].f[2], Dt[0][cc].f[3]); \
    unsigned p10 = cvtpk(Dt[1][cc].f[0], Dt[1][cc].f[1]); \
    unsigned p11 = cvtpk(Dt[1][cc].f[2], Dt[1][cc].f[3]); \
    unsigned p20 = cvtpk(Dt[2][cc].f[0], Dt[2][cc].f[1]); \
    unsigned p21 = cvtpk(Dt[2][cc].f[2], Dt[2][cc].f[3]); \
    unsigned p30 = cvtpk(Dt[3][cc].f[0], Dt[3][cc].f[1]); \
    unsigned p31 = cvtpk(Dt[3][cc].f[2], Dt[3][cc].f[3]); \
    swap32(p00, p10); swap32(p01, p11); swap32(p20, p30); swap32(p21, p31); \
    swap16(p00, p10); swap16(p01, p11); swap16(p20, p30); swap16(p21, p31); \
    P[0][cc].u[0]=p00; P[0][cc].u[1]=p01; P[0][cc].u[2]=p10; P[0][cc].u[3]=p11; \
    P[1][cc].u[0]=p20; P[1][cc].u[1]=p21; P[1][cc].u[2]=p30; P[1][cc].u[3]=p31; } } while(0)

#define MFMAB() do { _Pragma("unroll") \
  for (int cc=0;cc<4;++cc) { _Pragma("unroll") \
    for (int tt=0;tt<4;++tt) { \
      f32x4 acc = MFMA16(EA[tt][0].v, P[0][cc].v, zf); \
      Dt[tt][cc].v = MFMA16(EA[tt][1].v, P[1][cc].v, acc); } } } while(0)

#define STOREP(DST) do { _Pragma("unroll") \
  for (int cc=0;cc<4;++cc) { _Pragma("unroll") \
    for (int c=0;c<2;++c) { \
      uint4 q; q.x=P[c][cc].u[0]; q.y=P[c][cc].u[1]; q.z=P[c][cc].u[2]; q.w=P[c][cc].u[3]; \
      *(uint4*)((DST) + (cc*2+c)*256) = q; } } } while(0)

// =========================================================================
// Phase 1: per-(batch, segment) partial products, improved:
//  - sT padded to stride 65 (bank-conflict-free setup; R12 showed 1M conflicts)
//  - all 16 per-step u values preloaded into registers (no in-loop load stall)
//  - ev for step i+1 computed during step i (shfl+exp off the critical path)
//  - constant rescale 2^-64 at step 7 (no 6-level shfl reduce)
// =========================================================================
__global__ __launch_bounds__(64, 2)
void crf_seg_kernel(const float* __restrict__ u, const float* __restrict__ trans,
                    const int* __restrict__ lengths,
                    unsigned* __restrict__ Mout, float* __restrict__ Cout) {
    const int bid  = blockIdx.x;
    const int b    = bid & (B_SIZE - 1);
    const int s    = bid >> 7;
    const int lane = threadIdx.x;
    const int col  = lane & 15;
    const int g    = lane >> 4;
    const float K = 1.4426950408889634f;
    const f32x4 zf = {0.f, 0.f, 0.f, 0.f};

    const int len = lengths[b];
    int n_act = len - 1 - s*SEGL;
    n_act = max(0, min(SEGL, n_act));
    unsigned* dst = Mout + (size_t)(b*SEGS + s) * 2048 + lane * 4;

    U8 P[2][4];
    if (n_act == 0) {           // identity segment
        IDP();
        STOREP(dst);
        if (lane == 0) Cout[b*SEGS + s] = 0.0f;
        return;
    }

    __shared__ float sT[64 * 65];   // padded: stride 65 floats
    {
#pragma unroll
        for (int k = 0; k < 64; ++k) sT[k*65 + lane] = trans[k*64 + lane];
    }
    __syncthreads();

    const bool front = (s < 8);
    U8 EA[4][2];
    if (!front) {
        // A-frags of E: lane holds E[16tt+col][32c+8g+j]
#pragma unroll
        for (int tt = 0; tt < 4; ++tt) {
#pragma unroll
            for (int c = 0; c < 2; ++c) {
                const float* p = &sT[(16*tt + col)*65 + 32*c + 8*g];
#pragma unroll
                for (int j2 = 0; j2 < 4; ++j2)
                    EA[tt][c].u[j2] = cvtpk(fexp2(p[2*j2]*K), fexp2(p[2*j2+1]*K));
            }
        }
    } else {
        // A-frags of E^T: lane holds E[32c+8g+j][16tt+col]
#pragma unroll
        for (int tt = 0; tt < 4; ++tt) {
#pragma unroll
            for (int c = 0; c < 2; ++c) {
#pragma unroll
                for (int j2 = 0; j2 < 4; ++j2) {
                    const int a0i = 32*c + 8*g + 2*j2;
                    EA[tt][c].u[j2] = cvtpk(fexp2(sT[a0i*65 + 16*tt + col] * K),
                                            fexp2(sT[(a0i+1)*65 + 16*tt + col] * K));
                }
            }
        }
    }

    // Preload the 16 per-step u rows (lane n holds u[t][b][n]); one wait total.
    const float* ub = u + (size_t)b * 64 + lane;
    float Ur[16];
    if (!front) {
        const int t0 = 16*s + 1;
#pragma unroll
        for (int i = 0; i < 16; ++i) Ur[i] = ub[(size_t)min(t0 + i, T_STEPS - 1) * BN_];
    } else {
        const int th = 16*s + n_act;           // descending t
#pragma unroll
        for (int i = 0; i < 16; ++i) Ur[i] = ub[(size_t)max(th - i, 0) * BN_];
    }

    float C = 0.0f;
    float ev[4][4];
    F4 Dt[4][4];
    { float eul = fexp2(Ur[0] * K); EVG(); }   // ev for step 0

    if (!front) {
        IDP();                                  // P = I
#pragma unroll 16
        for (int i = 0; i < 16; ++i) {
            if (i >= n_act) break;
            MFMAB();                            // Dt = E * P
            EVSCALE();                          // Dt = diag(eu_i) * Dt
            if (i == 7) RESCC();
            CVTP();                             // P = bf16(Dt)
            if (i < 15) { float eul = fexp2(Ur[i+1] * K); EVG(); }  // ev for i+1
        }
    } else {
        // Dt = I (f32, D-layout)
#pragma unroll
        for (int tt = 0; tt < 4; ++tt) {
#pragma unroll
            for (int cc = 0; cc < 4; ++cc) {
#pragma unroll
                for (int r = 0; r < 4; ++r)
                    Dt[tt][cc].f[r] = (tt == cc && 4*g + r == col) ? 1.0f : 0.0f;
            }
        }
#pragma unroll 16
        for (int i = 0; i < 16; ++i) {
            if (i >= n_act) break;
            EVSCALE();                          // Dt = diag(eu_t) * Dt
            if (i == 7) RESCC();
            CVTP();                             // P = bf16(Dt)
            MFMAB();                            // Dt = E^T * P
            if (i < 15) { float eul = fexp2(Ur[i+1] * K); EVG(); }
        }
        CVTP();                                 // final convert
    }

    STOREP(dst);
    if (lane == 0) Cout[b*SEGS + s] = C;
}

// =========================================================================
// Phase 2 (verbatim R9): two-wave fold per batch, 8 serial steps each.
// =========================================================================
#define MLOAD(SL, SEG) do { \
    const unsigned* _mp = mbase + (size_t)(SEG) * 2048; \
    const unsigned* _mq = _mp + 1024; \
    asm volatile("global_load_dwordx4 %0, %1, off"             : "=v"(SL[0].v) : "v"(_mp)); \
    asm volatile("global_load_dwordx4 %0, %1, off offset:1024" : "=v"(SL[1].v) : "v"(_mp)); \
    asm volatile("global_load_dwordx4 %0, %1, off offset:2048" : "=v"(SL[2].v) : "v"(_mp)); \
    asm volatile("global_load_dwordx4 %0, %1, off offset:3072" : "=v"(SL[3].v) : "v"(_mp)); \
    asm volatile("global_load_dwordx4 %0, %1, off"             : "=v"(SL[4].v) : "v"(_mq)); \
    asm volatile("global_load_dwordx4 %0, %1, off offset:1024" : "=v"(SL[5].v) : "v"(_mq)); \
    asm volatile("global_load_dwordx4 %0, %1, off offset:2048" : "=v"(SL[6].v) : "v"(_mq)); \
    asm volatile("global_load_dwordx4 %0, %1, off offset:3072" : "=v"(SL[7].v) : "v"(_mq)); \
} while (0)

#define PSTEP(WN, SL, LD) do { \
    wait##WN(); \
    U8 Af0, Af1; \
    { float vs = (g < 2) ? a0 : a1; \
      float f0=__shfl(vs,sbase+0,64), f1=__shfl(vs,sbase+1,64); \
      float f2=__shfl(vs,sbase+2,64), f3=__shfl(vs,sbase+3,64); \
      float f4=__shfl(vs,sbase+4,64), f5=__shfl(vs,sbase+5,64); \
      float f6=__shfl(vs,sbase+6,64), f7=__shfl(vs,sbase+7,64); \
      Af0.u[0]=cvtpk(f0,f1); Af0.u[1]=cvtpk(f2,f3); Af0.u[2]=cvtpk(f4,f5); Af0.u[3]=cvtpk(f6,f7); } \
    { float vs = (g < 2) ? a2 : a3; \
      float f0=__shfl(vs,sbase+0,64), f1=__shfl(vs,sbase+1,64); \
      float f2=__shfl(vs,sbase+2,64), f3=__shfl(vs,sbase+3,64); \
      float f4=__shfl(vs,sbase+4,64), f5=__shfl(vs,sbase+5,64); \
      float f6=__shfl(vs,sbase+6,64), f7=__shfl(vs,sbase+7,64); \
      Af1.u[0]=cvtpk(f0,f1); Af1.u[1]=cvtpk(f2,f3); Af1.u[2]=cvtpk(f4,f5); Af1.u[3]=cvtpk(f6,f7); } \
    f32x4 q0 = MFMA16(Af0.v, SL[0].v, zf); q0 = MFMA16(Af1.v, SL[1].v, q0); \
    f32x4 q1 = MFMA16(Af0.v, SL[2].v, zf); q1 = MFMA16(Af1.v, SL[3].v, q1); \
    f32x4 q2 = MFMA16(Af0.v, SL[4].v, zf); q2 = MFMA16(Af1.v, SL[5].v, q2); \
    f32x4 q3 = MFMA16(Af0.v, SL[6].v, zf); q3 = MFMA16(Af1.v, SL[7].v, q3); \
    float n0 = q0[0], n1 = q1[0], n2 = q2[0], n3 = q3[0]; \
    float mm = fmaxf(fmaxf(n0, n1), fmaxf(n2, n3)); \
    mm = fmaxf(mm, __shfl_xor(mm, 1, 64)); mm = fmaxf(mm, __shfl_xor(mm, 2, 64)); \
    mm = fmaxf(mm, __shfl_xor(mm, 4, 64)); mm = fmaxf(mm, __shfl_xor(mm, 8, 64)); \
    float inv = frcp(mm); C2 += LN2 * flog2(mm); \
    a0 = n0 * inv; a1 = n1 * inv; a2 = n2 * inv; a3 = n3 * inv; \
    if ((LD) >= 0) { MLOAD(SL, LD); } \
} while (0)

__global__ __launch_bounds__(128, 1)
void crf_comb_kernel(const float* __restrict__ u, const float* __restrict__ trans,
                     const unsigned* __restrict__ Mbuf, const float* __restrict__ Cseg,
                     float* __restrict__ out) {
    const int tid  = threadIdx.x;
    const int wid  = tid >> 6;           // 0 = front fold, 1 = back fold
    const int lane = tid & 63;
    const int col  = lane & 15;
    const int g    = lane >> 4;
    const int b    = blockIdx.x;
    const float K = 1.4426950408889634f, LN2 = 0.6931471805599453f;
    const f32x4 zf = {0.f, 0.f, 0.f, 0.f};

    __shared__ float sX[64], sY[64], sC[2];

    float a0, a1, a2, a3;
    if (wid == 0) {   // x = w0 = exp(u0 + tStart), row vector
        a0 = fexp2((u[(size_t)b*64 +  0 + col] + trans[( 0 + col)*64 + START_IDX]) * K);
        a1 = fexp2((u[(size_t)b*64 + 16 + col] + trans[(16 + col)*64 + START_IDX]) * K);
        a2 = fexp2((u[(size_t)b*64 + 32 + col] + trans[(32 + col)*64 + START_IDX]) * K);
        a3 = fexp2((u[(size_t)b*64 + 48 + col] + trans[(48 + col)*64 + START_IDX]) * K);
    } else {          // a = f = exp(tEnd), row vector
        a0 = fexp2(trans[END_IDX*64 +  0 + col] * K);
        a1 = fexp2(trans[END_IDX*64 + 16 + col] * K);
        a2 = fexp2(trans[END_IDX*64 + 32 + col] * K);
        a3 = fexp2(trans[END_IDX*64 + 48 + col] * K);
    }

    const int sbase = (lane & 48) | ((g & 1) << 3);
    const unsigned* mbase = Mbuf + (size_t)b * SEGS * 2048 + lane * 4;

    U8 MP0[8], MP1[8], MP2[8], MP3[8];
    float C2 = 0.0f;

    if (wid == 0) {
        MLOAD(MP0, 0); MLOAD(MP1, 1); MLOAD(MP2, 2); MLOAD(MP3, 3);
        PSTEP(24, MP0,  4); PSTEP(24, MP1,  5); PSTEP(24, MP2,  6); PSTEP(24, MP3,  7);
        PSTEP(24, MP0, -1); PSTEP(16, MP1, -1); PSTEP(8,  MP2, -1); PSTEP(0,  MP3, -1);
    } else {
        MLOAD(MP0, 15); MLOAD(MP1, 14); MLOAD(MP2, 13); MLOAD(MP3, 12);
        PSTEP(24, MP0, 11); PSTEP(24, MP1, 10); PSTEP(24, MP2,  9); PSTEP(24, MP3,  8);
        PSTEP(24, MP0, -1); PSTEP(16, MP1, -1); PSTEP(8,  MP2, -1); PSTEP(0,  MP3, -1);
    }

    if (g == 0) {
        float* dstv = wid ? sY : sX;
        dstv[ 0 + col] = a0; dstv[16 + col] = a1;
        dstv[32 + col] = a2; dstv[48 + col] = a3;
    }
    if (wid == 1) {
        float cs = (lane < SEGS) ? Cseg[b*SEGS + lane] : 0.0f;
#pragma unroll
        for (int m = 1; m < 64; m <<= 1) cs += __shfl_xor(cs, m, 64);
        if (lane == 0) sC[1] = C2 + cs;
    } else if (lane == 0) sC[0] = C2;
    __syncthreads();

    if (tid < 16) {
        float part = 0.0f;
#pragma unroll
        for (int cc = 0; cc < 4; ++cc)
            part = fmaf(sX[16*cc + tid], sY[16*cc + tid], part);
        part += __shfl_xor(part, 1, 64);
        part += __shfl_xor(part, 2, 64);
        part += __shfl_xor(part, 4, 64);
        part += __shfl_xor(part, 8, 64);
        if (tid == 0) out[b] = sC[0] + sC[1] + LN2 * flog2(part);
    }
}

// =========================================================================
// Fallback (ws too small): serial fwd/bwd kernel (R6 lineage, verbatim R12).
// =========================================================================
#define LOAD4O(RB, PTR) do { const float* _p = (PTR); \
    asm volatile("global_load_dwordx4 %0, %1, off"            : "=v"(RB[0].v) : "v"(_p)); \
    asm volatile("global_load_dwordx4 %0, %1, off offset:64"  : "=v"(RB[1].v) : "v"(_p)); \
    asm volatile("global_load_dwordx4 %0, %1, off offset:128" : "=v"(RB[2].v) : "v"(_p)); \
    asm volatile("global_load_dwordx4 %0, %1, off offset:192" : "=v"(RB[3].v) : "v"(_p)); \
} while (0)

template<bool RS, bool SNAPW>
__device__ __forceinline__ void stepfn(F4 (&D)[4], F4 (&UB)[4], const U8 (&A)[4][2],
                                       bool ccw, F4 (&wS)[4], float &snapC, float &C) {
    const float K = 1.4426950408889634f, LN2 = 0.6931471805599453f;
    const f32x4 zf = {0.f, 0.f, 0.f, 0.f};
    F4 W[4];
#pragma unroll
    for (int tt = 0; tt < 4; ++tt) {
#pragma unroll
        for (int r = 0; r < 4; ++r) W[tt].f[r] = D[tt].f[r] * fexp2(UB[tt].f[r] * K);
    }
    if (RS) {
        float m0 = fmaxf(fmaxf(W[0].f[0], W[0].f[1]), fmaxf(W[0].f[2], W[0].f[3]));
        float m1 = fmaxf(fmaxf(W[1].f[0], W[1].f[1]), fmaxf(W[1].f[2], W[1].f[3]));
        float m2 = fmaxf(fmaxf(W[2].f[0], W[2].f[1]), fmaxf(W[2].f[2], W[2].f[3]));
        float m3 = fmaxf(fmaxf(W[3].f[0], W[3].f[1]), fmaxf(W[3].f[2], W[3].f[3]));
        float mm = fmaxf(fmaxf(m0, m1), fmaxf(m2, m3));
        mm = fmaxf(mm, __shfl_xor(mm, 16, 64));
        mm = fmaxf(mm, __shfl_xor(mm, 32, 64));
        float inv = frcp(mm);
        C += LN2 * flog2(mm);
        f32x2 iv; iv[0] = inv; iv[1] = inv;
#pragma unroll
        for (int tt = 0; tt < 4; ++tt) {
            W[tt].h[0] = pkmul(W[tt].h[0], iv);
            W[tt].h[1] = pkmul(W[tt].h[1], iv);
        }
    }
    if (SNAPW) {
        if (__ballot(ccw)) {
#pragma unroll
            for (int tt = 0; tt < 4; ++tt) {
#pragma unroll
                for (int r = 0; r < 4; ++r)
                    wS[tt].f[r] = ccw ? W[tt].f[r] : wS[tt].f[r];
            }
            snapC = ccw ? C : snapC;
        }
    }
    unsigned p00 = cvtpk(W[0].f[0], W[0].f[1]), p01 = cvtpk(W[0].f[2], W[0].f[3]);
    unsigned p10 = cvtpk(W[1].f[0], W[1].f[1]), p11 = cvtpk(W[1].f[2], W[1].f[3]);
    unsigned p20 = cvtpk(W[2].f[0], W[2].f[1]), p21 = cvtpk(W[2].f[2], W[2].f[3]);
    unsigned p30 = cvtpk(W[3].f[0], W[3].f[1]), p31 = cvtpk(W[3].f[2], W[3].f[3]);
    swap32(p00, p10); swap32(p01, p11); swap32(p20, p30); swap32(p21, p31);
    swap16(p00, p10); swap16(p01, p11); swap16(p20, p30); swap16(p21, p31);
    U8 b0, b1;
    b0.u[0] = p00; b0.u[1] = p01; b0.u[2] = p10; b0.u[3] = p11;
    b1.u[0] = p20; b1.u[1] = p21; b1.u[2] = p30; b1.u[3] = p31;
#pragma unroll
    for (int tt = 0; tt < 4; ++tt) {
        f32x4 acc = MFMA16(A[tt][0].v, b0.v, zf);
        D[tt].v   = MFMA16(A[tt][1].v, b1.v, acc);
    }
}

__device__ __forceinline__ void make_frags(const float* sT, int wid, int col, int g,
                                           U8 (&A)[4][2], F4 (&D)[4]) {
    const float K = 1.4426950408889634f;
    if (wid == 0) {
#pragma unroll
        for (int tt = 0; tt < 4; ++tt) {
#pragma unroll
            for (int c = 0; c < 2; ++c) {
                const float* p = &sT[(16*tt + col)*64 + 32*c + 8*g];
#pragma unroll
                for (int j2 = 0; j2 < 4; ++j2)
                    A[tt][c].u[j2] = cvtpk(fexp2(p[2*j2]*K), fexp2(p[2*j2+1]*K));
            }
        }
#pragma unroll
        for (int tt = 0; tt < 4; ++tt) {
#pragma unroll
            for (int r = 0; r < 4; ++r)
                D[tt].f[r] = fexp2(sT[(16*tt + 4*g + r)*64 + START_IDX] * K);
        }
    } else {
#pragma unroll
        for (int tt = 0; tt < 4; ++tt) {
#pragma unroll
            for (int c = 0; c < 2; ++c) {
#pragma unroll
                for (int j2 = 0; j2 < 4; ++j2) {
                    const int a0 = 32*c + 8*g + 2*j2;
                    A[tt][c].u[j2] = cvtpk(fexp2(sT[a0*64 + 16*tt + col] * K),
                                           fexp2(sT[(a0+1)*64 + 16*tt + col] * K));
                }
            }
        }
#pragma unroll
        for (int tt = 0; tt < 4; ++tt) {
#pragma unroll
            for (int r = 0; r < 4; ++r)
                D[tt].f[r] = fexp2(sT[END_IDX*64 + 16*tt + 4*g + r] * K);
        }
    }
}

__launch_bounds__(128, 1)
__global__ void crf_fb_old(const float* __restrict__ src,
                           const float* __restrict__ trans,
                           const int* __restrict__ lengths,
                           float* __restrict__ out) {
    const int tid  = threadIdx.x;
    const int wid  = tid >> 6;
    const int lane = tid & 63;
    const int col  = lane & 15;
    const int g    = lane >> 4;
    const int bidx = blockIdx.x * 16 + col;

    __shared__ __align__(16) float sT[N_TAGS * N_TAGS];
    __shared__ __align__(16) float sW[N_TAGS * 16];
    __shared__ __align__(16) float sV[N_TAGS * 16];
    __shared__ float sCf[16], sCb[16];

    {
        const float4* t4 = (const float4*)trans;
        float4* s4 = (float4*)sT;
#pragma unroll
        for (int k2 = 0; k2 < 8; ++k2) s4[k2 * 128 + tid] = t4[k2 * 128 + tid];
    }
    __syncthreads();

    const float LN2 = 0.6931471805599453f;
    const int len = lengths[bidx];
    const int M   = (len - 1) >> 1;
    const int Kb  = (len - 1) - M;

    U8 A[4][2];
    F4 D[4];
    make_frags(sT, wid, col, g, A, D);

    int need = (wid == 0) ? (M + 1) : Kb;
    int mx = need;
#pragma unroll
    for (int m = 1; m < 64; m <<= 1) mx = max(mx, __shfl_xor(mx, m, 64));
    mx = __builtin_amdgcn_readfirstlane(mx);

    const int base = bidx * 64 + 4 * g;
    float C = 0.0f, snapC = 0.0f;
    F4 wS[4];
#pragma unroll
    for (int tt = 0; tt < 4; ++tt) wS[tt] = D[tt];

    F4 R0[4], R1[4], R2[4], R3[4], R4_[4], R5[4], R6[4], R7[4];

    if (wid == 0) {
        const float* pf = src + base;
        LOAD4O(R0, pf);            LOAD4O(R1, pf + BN_);
        LOAD4O(R2, pf + 2*BN_);    LOAD4O(R3, pf + 3*BN_);
        LOAD4O(R4_, pf + 4*BN_);   LOAD4O(R5, pf + 5*BN_);
        LOAD4O(R6, pf + 6*BN_);    LOAD4O(R7, pf + 7*BN_);
        const float* pn = pf + 8 * BN_;
        const int Nf = (mx + 7) & ~7;
        for (int s = 0; s < Nf; s += 8) {
#define FSTEP(QQ, RB, RSF) do { \
            const int t_ = s + (QQ); \
            wait28(); \
            stepfn<RSF, true>(D, RB, A, (t_ == M), wS, snapC, C); \
            LOAD4O(RB, pn); pn += BN_; \
        } while (0)
            FSTEP(0, R0, false); FSTEP(1, R1, false); FSTEP(2, R2, false);
            FSTEP(3, R3, false); FSTEP(4, R4_, false); FSTEP(5, R5, false);
            FSTEP(6, R6, false); FSTEP(7, R7, true);
#undef FSTEP
        }
        wait0();
    } else {
        const float* pb = src + base;
        {
#define PRIME(RB, q) do { int tq = max(len - 1 - (q), 0); LOAD4O(RB, pb + tq * BN_); } while (0)
            PRIME(R0, 0); PRIME(R1, 1); PRIME(R2, 2); PRIME(R3, 3);
            PRIME(R4_, 4); PRIME(R5, 5); PRIME(R6, 6); PRIME(R7, 7);
#undef PRIME
        }
        int tP = len - 9;
        const int Nb = (mx + 7) & ~7;
        for (int s = 0; s < Nb; s += 8) {
#define BSTEP(QQ, RB, RSF) do { \
            const int k_ = s + (QQ) + 1; \
            wait28(); \
            stepfn<RSF, false>(D, RB, A, false, wS, snapC, C); \
            if (__ballot(k_ == Kb)) { \
                const bool cc = (k_ == Kb); \
                _Pragma("unroll") \
                for (int tt = 0; tt < 4; ++tt) { \
                    _Pragma("unroll") \
                    for (int r = 0; r < 4; ++r) \
                        wS[tt].f[r] = cc ? D[tt].f[r] : wS[tt].f[r]; \
                } \
                snapC = cc ? C : snapC; \
            } \
            int tc = max(tP, 0); LOAD4O(RB, pb + tc * BN_); tP -= 1; \
        } while (0)
            BSTEP(0, R0, false); BSTEP(1, R1, false); BSTEP(2, R2, false);
            BSTEP(3, R3, false); BSTEP(4, R4_, false); BSTEP(5, R5, false);
            BSTEP(6, R6, false); BSTEP(7, R7, true);
#undef BSTEP
        }
        wait0();
    }

    {
        float* dstv = (wid == 0) ? sW : sV;
#pragma unroll
        for (int tt = 0; tt < 4; ++tt) {
#pragma unroll
            for (int r = 0; r < 4; ++r)
                dstv[(16*tt + 4*g + r) * 16 + col] = wS[tt].f[r];
        }
        if (g == 0) { if (wid == 0) sCf[col] = snapC; else sCb[col] = snapC; }
    }
    __syncthreads();
    if (wid == 0) {
        float part = 0.0f;
#pragma unroll
        for (int j = 0; j < 16; ++j) {
            const int n = g * 16 + j;
            part = fmaf(sW[n * 16 + col], sV[n * 16 + col], part);
        }
        part += __shfl_xor(part, 16, 64);
        part += __shfl_xor(part, 32, 64);
        if (g == 0) out[bidx] = sCf[col] + sCb[col] + LN2 * flog2(part);
    }
}

extern "C" void kernel_launch(void* const* d_in, const int* in_sizes, int n_in,
                              void* d_out, int out_size, void* d_ws, size_t ws_size,
                              hipStream_t stream) {
    const float* unary   = (const float*)d_in[0];
    const float* trans   = (const float*)d_in[1];
    const int*   lengths = (const int*)d_in[2];
    float* out = (float*)d_out;

    const size_t mcount = (size_t)B_SIZE * SEGS * 2048;       // u32 elements
    const size_t need   = mcount * 4 + (size_t)B_SIZE * SEGS * 4;
    if (ws_size >= need) {
        unsigned* Mbuf = (unsigned*)d_ws;
        float* Cseg = (float*)((unsigned*)d_ws + mcount);
        hipLaunchKernelGGL(crf_seg_kernel, dim3(B_SIZE * SEGS), dim3(64), 0, stream,
                           unary, trans, lengths, Mbuf, Cseg);
        hipLaunchKernelGGL(crf_comb_kernel, dim3(B_SIZE), dim3(128), 0, stream,
                           unary, trans, Mbuf, Cseg, out);
    } else {
        hipLaunchKernelGGL(crf_fb_old, dim3(B_SIZE / 16), dim3(128), 0, stream,
                           unary, trans, lengths, out);
    }
}